// Round 1
// baseline (2336.130 us; speedup 1.0000x reference)
//
#include <hip/hip_runtime.h>
#include <hip/hip_bf16.h>
#include <stdint.h>

// Problem dims (fixed by setup_inputs)
constexpr int T  = 4 * 2048;   // tokens = B*S
constexpr int H  = 1536;
constexpr int I2 = 6144;       // 2 * intermediate
constexpr int II = 3072;       // intermediate
constexpr int EE = 16;         // experts
#define ALPHA_ 1.702f
#define LIMIT_ 7.0f
#define EPS_   1e-6f

typedef unsigned short u16;
typedef __bf16 bf16x8 __attribute__((ext_vector_type(8)));
typedef float  f32x4  __attribute__((ext_vector_type(4)));

__device__ __forceinline__ u16 f2bf(float f) {
  union { float f; unsigned int u; } c; c.f = f;
  unsigned int u = c.u + 0x7fffu + ((c.u >> 16) & 1u);  // RTNE
  return (u16)(u >> 16);
}
__device__ __forceinline__ unsigned int pack2(float lo, float hi) {
  return (unsigned int)f2bf(lo) | ((unsigned int)f2bf(hi) << 16);
}

// async global->LDS, 16B per lane. LDS dest must be wave-uniform base + lane*16.
__device__ __forceinline__ void async16(const void* g, void* l) {
  __builtin_amdgcn_global_load_lds(
      (const __attribute__((address_space(1))) unsigned int*)(uintptr_t)g,
      (__attribute__((address_space(3))) unsigned int*)(unsigned int)(uintptr_t)l,
      16, 0, 0);
}

// ---------------- K1: RMSNorm + router logits ----------------
__global__ __launch_bounds__(256) void k_rms_router(
    const float* __restrict__ x, const float* __restrict__ nscale,
    const float* __restrict__ gw, u16* __restrict__ xnb,
    float* __restrict__ logits) {
  const int t = blockIdx.x;
  const int tid = threadIdx.x;
  const int lane = tid & 63, wid = tid >> 6;
  const float* xr = x + (size_t)t * H;
  float v[6]; float ss = 0.f;
#pragma unroll
  for (int j = 0; j < 6; ++j) { v[j] = xr[tid + j * 256]; ss += v[j] * v[j]; }
  __shared__ float red[4];
  for (int off = 32; off; off >>= 1) ss += __shfl_down(ss, off, 64);
  if (lane == 0) red[wid] = ss;
  __syncthreads();
  const float rs = rsqrtf((red[0] + red[1] + red[2] + red[3]) * (1.0f / H) + EPS_);
  float xn[6];
#pragma unroll
  for (int j = 0; j < 6; ++j) {
    const int i = tid + j * 256;
    xn[j] = v[j] * rs * nscale[i];
    xnb[(size_t)t * H + i] = f2bf(xn[j]);
  }
  float acc[16];
#pragma unroll
  for (int e = 0; e < 16; ++e) acc[e] = 0.f;
#pragma unroll
  for (int j = 0; j < 6; ++j) {
    const int i = tid + j * 256;
#pragma unroll
    for (int e = 0; e < 16; ++e) acc[e] += xn[j] * gw[e * H + i];
  }
  __shared__ float lred[4][16];
#pragma unroll
  for (int e = 0; e < 16; ++e) {
    float a = acc[e];
    for (int off = 32; off; off >>= 1) a += __shfl_down(a, off, 64);
    if (lane == 0) lred[wid][e] = a;
  }
  __syncthreads();
  if (tid < 16)
    logits[(size_t)t * 16 + tid] = lred[0][tid] + lred[1][tid] + lred[2][tid] + lred[3][tid];
}

// ---------------- K2: per-token top-4 + softmax; token-0 expert ids ----------------
__global__ __launch_bounds__(256) void k_topk(
    const float* __restrict__ logits, float* __restrict__ probs, int* __restrict__ eids) {
  const int t = blockIdx.x * 256 + threadIdx.x;
  if (t >= T) return;
  float v[16];
#pragma unroll
  for (int e = 0; e < 16; ++e) v[e] = logits[(size_t)t * 16 + e];
  float tv[4]; int ti[4]; unsigned used = 0;
#pragma unroll
  for (int j = 0; j < 4; ++j) {
    float best = -3.4e38f; int bi = 0;
#pragma unroll
    for (int e = 0; e < 16; ++e) {
      if (!((used >> e) & 1u) && v[e] > best) { best = v[e]; bi = e; }
    }
    used |= 1u << bi; tv[j] = best; ti[j] = bi;
  }
  const float m = tv[0];
  float ex[4], den = 0.f;
#pragma unroll
  for (int j = 0; j < 4; ++j) { ex[j] = __expf(tv[j] - m); den += ex[j]; }
  const float rden = 1.0f / den;
#pragma unroll
  for (int j = 0; j < 4; ++j) probs[(size_t)t * 4 + j] = ex[j] * rden;
  if (t == 0) {
#pragma unroll
    for (int j = 0; j < 4; ++j) eids[j] = ti[j] % EE;
  }
}

// ---------------- K3a: gather biases for the 4 selected experts ----------------
__global__ __launch_bounds__(256) void k_gather_bias(
    const float* __restrict__ bup, const float* __restrict__ bdn,
    const int* __restrict__ eids, float* __restrict__ bu_g, float* __restrict__ bd_g) {
  const int i = blockIdx.x * 256 + threadIdx.x;   // grid sized exactly 4*I2+4*H
  if (i < 4 * I2) {
    const int s = i / I2, r = i - s * I2;
    bu_g[i] = bup[(size_t)eids[s] * I2 + r];
  } else {
    const int j = i - 4 * I2;
    const int s = j / H, r = j - s * H;
    bd_g[j] = bdn[(size_t)eids[s] * H + r];
  }
}

// ---------------- K3b: gather + fp32->bf16 convert selected expert weights ----------------
__global__ __launch_bounds__(256) void k_gather_w(
    const float* __restrict__ wup, const float* __restrict__ wdn,
    const int* __restrict__ eids, u16* __restrict__ wu_b, u16* __restrict__ wd_b) {
  const size_t UP = (size_t)4 * I2 * H;
  const size_t u = ((size_t)blockIdx.x * 256 + threadIdx.x) * 8;  // grid sized exactly
  if (u < UP) {
    const int s = (int)(u / ((size_t)I2 * H));
    const size_t r = u - (size_t)s * I2 * H;
    const float4* src = (const float4*)(wup + (size_t)eids[s] * I2 * H + r);
    const float4 a = src[0], b = src[1];
    uint4 o; o.x = pack2(a.x, a.y); o.y = pack2(a.z, a.w);
    o.z = pack2(b.x, b.y); o.w = pack2(b.z, b.w);
    *(uint4*)(wu_b + u) = o;
  } else {
    const size_t q = u - UP;
    const int s = (int)(q / ((size_t)H * II));
    const size_t r = q - (size_t)s * H * II;
    const float4* src = (const float4*)(wdn + (size_t)eids[s] * H * II + r);
    const float4 a = src[0], b = src[1];
    uint4 o; o.x = pack2(a.x, a.y); o.y = pack2(a.z, a.w);
    o.z = pack2(b.x, b.y); o.w = pack2(b.z, b.w);
    *(uint4*)(wd_b + q) = o;
  }
}

// ---------------- K4: GEMM1 (xn @ w_up^T) + bias + SwiGLU + prob scale -> act(bf16) ----------------
// Tile: 128(M) x 64(N of II), dual B tiles (g rows n, l rows II+n). 256 thr = 2x2 waves, wave = 64x32.
__global__ __launch_bounds__(256) void k_gemm1(
    const u16* __restrict__ xnb, const u16* __restrict__ wu_b,
    const float* __restrict__ bu_g, const float* __restrict__ probs,
    u16* __restrict__ act) {
  const int s  = blockIdx.z;
  const int n0 = blockIdx.x * 64;
  const int m0 = blockIdx.y * 128;
  const int tid = threadIdx.x;
  const int lane = tid & 63, wid = tid >> 6;
  const int wm = wid >> 1, wn = wid & 1;
  __shared__ u16 As[128 * 32];
  __shared__ u16 Bg[64 * 32];
  __shared__ u16 Bl[64 * 32];
  const u16* wug = wu_b + (size_t)s * I2 * H;
  f32x4 accg[4][2], accl[4][2];
  const f32x4 z = {0.f, 0.f, 0.f, 0.f};
#pragma unroll
  for (int i = 0; i < 4; ++i)
#pragma unroll
    for (int j = 0; j < 2; ++j) { accg[i][j] = z; accl[i][j] = z; }
  const int row2 = tid >> 2, cg = tid & 3;
  for (int k0 = 0; k0 < H; k0 += 32) {
    async16(xnb + (size_t)(m0 + row2) * H + k0 + cg * 8,        &As[tid * 8]);
    async16(xnb + (size_t)(m0 + 64 + row2) * H + k0 + cg * 8,   &As[2048 + tid * 8]);
    async16(wug + (size_t)(n0 + row2) * H + k0 + cg * 8,        &Bg[tid * 8]);
    async16(wug + (size_t)(II + n0 + row2) * H + k0 + cg * 8,   &Bl[tid * 8]);
    __syncthreads();
    const int quad = (lane >> 4) * 8, r16 = lane & 15;
    bf16x8 a[4], bg[2], bl[2];
#pragma unroll
    for (int i = 0; i < 4; ++i) a[i] = *(const bf16x8*)&As[(wm * 64 + i * 16 + r16) * 32 + quad];
#pragma unroll
    for (int j = 0; j < 2; ++j) {
      bg[j] = *(const bf16x8*)&Bg[(wn * 32 + j * 16 + r16) * 32 + quad];
      bl[j] = *(const bf16x8*)&Bl[(wn * 32 + j * 16 + r16) * 32 + quad];
    }
#pragma unroll
    for (int i = 0; i < 4; ++i)
#pragma unroll
      for (int j = 0; j < 2; ++j) {
        accg[i][j] = __builtin_amdgcn_mfma_f32_16x16x32_bf16(a[i], bg[j], accg[i][j], 0, 0, 0);
        accl[i][j] = __builtin_amdgcn_mfma_f32_16x16x32_bf16(a[i], bl[j], accl[i][j], 0, 0, 0);
      }
    __syncthreads();
  }
  // epilogue: bias, SwiGLU, per-row prob, store bf16
  u16* actS = act + (size_t)s * T * II;
  const int crow0 = m0 + wm * 64, ccol0 = n0 + wn * 32;
#pragma unroll
  for (int i = 0; i < 4; ++i) {
#pragma unroll
    for (int j = 0; j < 2; ++j) {
      const int col = ccol0 + j * 16 + (lane & 15);
      const float bug = bu_g[s * I2 + col];
      const float bul = bu_g[s * I2 + II + col];
#pragma unroll
      for (int r = 0; r < 4; ++r) {
        const int row = crow0 + i * 16 + (lane >> 4) * 4 + r;
        float g = accg[i][j][r] + bug;
        float l = accl[i][j][r] + bul;
        g = fminf(g, LIMIT_);
        l = fminf(fmaxf(l, -LIMIT_), LIMIT_);
        const float sig = 1.0f / (1.0f + __expf(-ALPHA_ * g));
        const float a = g * sig * (l + 1.0f);
        const float p = probs[(size_t)row * 4 + s];
        actS[(size_t)row * II + col] = f2bf(a * p);
      }
    }
  }
}

// ---------------- K5: GEMM2 over all 4 slots (K=4*II) + residual + bias ----------------
// Tile: 128x128, 256 thr = 2x2 waves, wave = 64x64.
__global__ __launch_bounds__(256) void k_gemm2(
    const u16* __restrict__ act, const u16* __restrict__ wd_b,
    const float* __restrict__ bd_g, const float* __restrict__ probs,
    const float* __restrict__ x, float* __restrict__ out) {
  const int n0 = blockIdx.x * 128;   // H
  const int m0 = blockIdx.y * 128;   // T
  const int tid = threadIdx.x;
  const int lane = tid & 63, wid = tid >> 6;
  const int wm = wid >> 1, wn = wid & 1;
  __shared__ u16 As[128 * 32];
  __shared__ u16 Bs[128 * 32];
  f32x4 acc[4][4];
  const f32x4 z = {0.f, 0.f, 0.f, 0.f};
#pragma unroll
  for (int i = 0; i < 4; ++i)
#pragma unroll
    for (int j = 0; j < 4; ++j) acc[i][j] = z;
  const int row2 = tid >> 2, cg = tid & 3;
  for (int s = 0; s < 4; ++s) {
    const u16* Ab = act + (size_t)s * T * II;
    const u16* Bb = wd_b + (size_t)s * H * II;
    for (int k0 = 0; k0 < II; k0 += 32) {
      async16(Ab + (size_t)(m0 + row2) * II + k0 + cg * 8,      &As[tid * 8]);
      async16(Ab + (size_t)(m0 + 64 + row2) * II + k0 + cg * 8, &As[2048 + tid * 8]);
      async16(Bb + (size_t)(n0 + row2) * II + k0 + cg * 8,      &Bs[tid * 8]);
      async16(Bb + (size_t)(n0 + 64 + row2) * II + k0 + cg * 8, &Bs[2048 + tid * 8]);
      __syncthreads();
      const int quad = (lane >> 4) * 8, r16 = lane & 15;
      bf16x8 a[4], b[4];
#pragma unroll
      for (int i = 0; i < 4; ++i) a[i] = *(const bf16x8*)&As[(wm * 64 + i * 16 + r16) * 32 + quad];
#pragma unroll
      for (int j = 0; j < 4; ++j) b[j] = *(const bf16x8*)&Bs[(wn * 64 + j * 16 + r16) * 32 + quad];
#pragma unroll
      for (int i = 0; i < 4; ++i)
#pragma unroll
        for (int j = 0; j < 4; ++j)
          acc[i][j] = __builtin_amdgcn_mfma_f32_16x16x32_bf16(a[i], b[j], acc[i][j], 0, 0, 0);
      __syncthreads();
    }
  }
#pragma unroll
  for (int i = 0; i < 4; ++i) {
#pragma unroll
    for (int r = 0; r < 4; ++r) {
      const int row = m0 + wm * 64 + i * 16 + (lane >> 4) * 4 + r;
      const float p0 = probs[(size_t)row * 4 + 0], p1 = probs[(size_t)row * 4 + 1];
      const float p2 = probs[(size_t)row * 4 + 2], p3 = probs[(size_t)row * 4 + 3];
#pragma unroll
      for (int j = 0; j < 4; ++j) {
        const int col = n0 + wn * 64 + j * 16 + (lane & 15);
        const float bias = p0 * bd_g[col] + p1 * bd_g[H + col] +
                           p2 * bd_g[2 * H + col] + p3 * bd_g[3 * H + col];
        out[(size_t)row * H + col] = x[(size_t)row * H + col] + acc[i][j][r] + bias;
      }
    }
  }
}

extern "C" void kernel_launch(void* const* d_in, const int* in_sizes, int n_in,
                              void* d_out, int out_size, void* d_ws, size_t ws_size,
                              hipStream_t stream) {
  const float* x      = (const float*)d_in[0];
  const float* nscale = (const float*)d_in[1];
  const float* gw     = (const float*)d_in[2];
  const float* wup    = (const float*)d_in[3];
  const float* bup    = (const float*)d_in[4];
  const float* wdn    = (const float*)d_in[5];
  const float* bdn    = (const float*)d_in[6];
  float* out = (float*)d_out;
  char* ws = (char*)d_ws;
  size_t off = 0;
  auto alloc = [&](size_t bytes) { size_t o = off; off += (bytes + 255) & ~(size_t)255; return o; };
  u16*   xnb    = (u16*)(ws + alloc((size_t)T * H * 2));       // 25.2 MB
  float* logits = (float*)(ws + alloc((size_t)T * 16 * 4));    // 0.5 MB
  float* probs  = (float*)(ws + alloc((size_t)T * 4 * 4));     // 0.13 MB
  int*   eids   = (int*)(ws + alloc(64));
  float* bu_g   = (float*)(ws + alloc((size_t)4 * I2 * 4));
  float* bd_g   = (float*)(ws + alloc((size_t)4 * H * 4));
  u16*   wu_b   = (u16*)(ws + alloc((size_t)4 * I2 * H * 2));  // 75.5 MB
  u16*   wd_b   = (u16*)(ws + alloc((size_t)4 * H * II * 2));  // 37.7 MB
  u16*   act    = (u16*)(ws + alloc((size_t)4 * T * II * 2));  // 201 MB
  (void)ws_size; (void)in_sizes; (void)n_in; (void)out_size;   // total ~340.5 MB

  k_rms_router<<<T, 256, 0, stream>>>(x, nscale, gw, xnb, logits);
  k_topk<<<T / 256, 256, 0, stream>>>(logits, probs, eids);
  k_gather_bias<<<(4 * I2 + 4 * H) / 256, 256, 0, stream>>>(bup, bdn, eids, bu_g, bd_g);
  {
    const size_t total = (size_t)4 * I2 * H + (size_t)4 * H * II;
    k_gather_w<<<(unsigned)(total / 8 / 256), 256, 0, stream>>>(wup, wdn, eids, wu_b, wd_b);
  }
  k_gemm1<<<dim3(II / 64, T / 128, 4), 256, 0, stream>>>(xnb, wu_b, bu_g, probs, act);
  k_gemm2<<<dim3(H / 128, T / 128), 256, 0, stream>>>(act, wd_b, bd_g, probs, x, out);
}